// Round 8
// baseline (3757.468 us; speedup 1.0000x reference)
//
#include <hip/hip_runtime.h>
#include <cstddef>
#include <cstdint>

#define T_SEQ 1024
#define BATCH 256
#define HID   64
#define G3    192   // 3*H
#define CHK   128   // timesteps per chunk
#define NCHK  (T_SEQ / CHK)

typedef unsigned short ushort_t;

__device__ __forceinline__ float sigm_f(float x) {
    return __fdividef(1.f, 1.f + __expf(-x));
}
__device__ __forceinline__ float tanh_f(float x) {
    return 1.f - __fdividef(2.f, 1.f + __expf(2.f * x));
}
__device__ __forceinline__ ushort_t f2bf_rne(float f) {
    uint32_t u = __float_as_uint(f);
    uint32_t r = (u + 0x7FFFu + ((u >> 16) & 1u)) >> 16;
    return (ushort_t)r;
}
__device__ __forceinline__ float bf2f(ushort_t u) {
    return __uint_as_float(((uint32_t)u) << 16);
}

__device__ __forceinline__ float4 load4f(const float* p) { return *(const float4*)p; }
__device__ __forceinline__ float4 load4f(const ushort_t* p) {
    ushort4 u = *(const ushort4*)p;
    float4 f;
    f.x = bf2f(u.x); f.y = bf2f(u.y); f.z = bf2f(u.z); f.w = bf2f(u.w);
    return f;
}

// ---------------------------------------------------------------------------
// Chunked input GEMM.
// x: full (T, B, K) tensor (fp32 or bf16). w: (ndir, 192, K). bias: (ndir,192).
// gi out: (2, CHK*B, 192), chunk-local, time PRE-REVERSED for dir 1 so the
// recurrence reads i = 0..CHK-1 sequentially for both directions.
// Grid: (CHK*B/64, 3, ndir), 256 threads, 64x64 tile, 4x4 per thread.
// ---------------------------------------------------------------------------
template<typename TX, int K>
__global__ __launch_bounds__(256) void gi_gemm_chunk(
    const TX* __restrict__ x,
    const float* __restrict__ w,
    long w_dir_stride,
    const float* __restrict__ bias,
    long bias_dir_stride,
    float* __restrict__ gi,
    int c)
{
    __shared__ float xs[64][65];
    __shared__ float wsm[64][65];

    const int tid = threadIdx.x;
    const int mb  = blockIdx.x;       // [0, CHK*B/64)
    const int nb  = blockIdx.y;       // [0, 3)
    const int d   = blockIdx.z;

    const int t_local = mb >> 2;                 // B/64 = 4 tiles per timestep
    const int boff    = (mb & 3) * 64;
    const int t_glob  = d ? (T_SEQ - 1 - c * CHK - t_local) : (c * CHK + t_local);

    const TX*    xg = x + ((size_t)t_glob * BATCH + boff) * K;
    const float* wg = w + (size_t)d * w_dir_stride + (size_t)nb * 64 * K;
    float* op = gi + ((size_t)d * CHK * BATCH + (size_t)t_local * BATCH + boff) * G3 + nb * 64;

    const int r0 = (tid >> 4) << 2;
    const int c0 = (tid & 15) << 2;
    float acc[4][4] = {};

    for (int kc = 0; kc < K; kc += 64) {
        #pragma unroll
        for (int i = 0; i < 4; ++i) {
            int ch  = tid + i * 256;   // 1024 4-elem chunks = 64 rows x 16
            int row = ch >> 4;
            int col = (ch & 15) << 2;
            float4 v = load4f(xg + (size_t)row * K + kc + col);
            xs[row][col+0] = v.x; xs[row][col+1] = v.y;
            xs[row][col+2] = v.z; xs[row][col+3] = v.w;
            float4 u = load4f(wg + (size_t)row * K + kc + col);
            wsm[row][col+0] = u.x; wsm[row][col+1] = u.y;
            wsm[row][col+2] = u.z; wsm[row][col+3] = u.w;
        }
        __syncthreads();
        #pragma unroll 8
        for (int k = 0; k < 64; ++k) {
            float a0 = xs[r0+0][k], a1 = xs[r0+1][k], a2 = xs[r0+2][k], a3 = xs[r0+3][k];
            float b0 = wsm[c0+0][k], b1 = wsm[c0+1][k], b2 = wsm[c0+2][k], b3 = wsm[c0+3][k];
            acc[0][0] = fmaf(a0,b0,acc[0][0]); acc[0][1] = fmaf(a0,b1,acc[0][1]);
            acc[0][2] = fmaf(a0,b2,acc[0][2]); acc[0][3] = fmaf(a0,b3,acc[0][3]);
            acc[1][0] = fmaf(a1,b0,acc[1][0]); acc[1][1] = fmaf(a1,b1,acc[1][1]);
            acc[1][2] = fmaf(a1,b2,acc[1][2]); acc[1][3] = fmaf(a1,b3,acc[1][3]);
            acc[2][0] = fmaf(a2,b0,acc[2][0]); acc[2][1] = fmaf(a2,b1,acc[2][1]);
            acc[2][2] = fmaf(a2,b2,acc[2][2]); acc[2][3] = fmaf(a2,b3,acc[2][3]);
            acc[3][0] = fmaf(a3,b0,acc[3][0]); acc[3][1] = fmaf(a3,b1,acc[3][1]);
            acc[3][2] = fmaf(a3,b2,acc[3][2]); acc[3][3] = fmaf(a3,b3,acc[3][3]);
        }
        __syncthreads();
    }

    const float* bp = bias + (size_t)d * bias_dir_stride + nb * 64;
    float4 bv = *(const float4*)(bp + c0);
    #pragma unroll
    for (int i = 0; i < 4; ++i) {
        float4 o;
        o.x = acc[i][0] + bv.x; o.y = acc[i][1] + bv.y;
        o.z = acc[i][2] + bv.z; o.w = acc[i][3] + bv.w;
        *(float4*)(op + (size_t)(r0 + i) * G3 + c0) = o;
    }
}

// ---------------------------------------------------------------------------
// Chunked GRU recurrence. One 64-lane wave per (batch, dir); lane j owns unit
// j, Whh rows for unit j live in 192 VGPRs, 64-deep dot via readlane.
// gi: (2, CHK*B, 192) chunk-local (time pre-reversed for dir1).
// ys (bf16) full (T, B, 128) or null. hbuf: (2,B,64) fp32 carry.
// fin: pre-offset fp32 out pointer (row stride 128), only non-null on the
// final chunk; written by dir == fin_dir.
// ---------------------------------------------------------------------------
__global__ __launch_bounds__(64) void gru_recur_chunk(
    const float* __restrict__ gi,
    const float* __restrict__ WhhL,   // (2, 192, 64)
    const float* __restrict__ bhhL,   // (2, 192)
    ushort_t* __restrict__ ys,
    float* __restrict__ hbuf,
    float* __restrict__ fin,
    int fin_dir,
    int c)
{
    const int b = blockIdx.x;
    const int d = blockIdx.y;
    const int j = threadIdx.x;

    const float* W = WhhL + (size_t)d * G3 * HID;
    float wr[HID], wz[HID], wn[HID];
    #pragma unroll
    for (int q = 0; q < HID / 4; ++q) {
        float4 a = *(const float4*)(W + (size_t)j * HID + 4*q);
        wr[4*q+0] = a.x; wr[4*q+1] = a.y; wr[4*q+2] = a.z; wr[4*q+3] = a.w;
        float4 bq = *(const float4*)(W + (size_t)(HID + j) * HID + 4*q);
        wz[4*q+0] = bq.x; wz[4*q+1] = bq.y; wz[4*q+2] = bq.z; wz[4*q+3] = bq.w;
        float4 cq = *(const float4*)(W + (size_t)(2*HID + j) * HID + 4*q);
        wn[4*q+0] = cq.x; wn[4*q+1] = cq.y; wn[4*q+2] = cq.z; wn[4*q+3] = cq.w;
    }
    const float* bh = bhhL + (size_t)d * G3;
    const float bhr = bh[j], bhz = bh[HID + j], bhn = bh[2*HID + j];

    const float* gib = gi + (size_t)d * CHK * BATCH * G3;

    float h = (c == 0) ? 0.f : hbuf[((size_t)d * BATCH + b) * HID + j];

    auto gaddr = [&](int i) -> const float* {
        return gib + ((size_t)i * BATCH + b) * G3;
    };

    const float* p = gaddr(0);
    float grA = p[j], gzA = p[HID + j], gnA = p[2*HID + j];
    p = gaddr(1);
    float grB = p[j], gzB = p[HID + j], gnB = p[2*HID + j];

    auto step = [&](float gr, float gz, float gn, int i_) {
        float accr = bhr, accz = bhz, accn = bhn;
        #pragma unroll
        for (int k = 0; k < HID; ++k) {
            float hk = __int_as_float(__builtin_amdgcn_readlane(__float_as_int(h), k));
            accr = fmaf(hk, wr[k], accr);
            accz = fmaf(hk, wz[k], accz);
            accn = fmaf(hk, wn[k], accn);
        }
        float r = sigm_f(gr + accr);
        float z = sigm_f(gz + accz);
        float n = tanh_f(gn + r * accn);
        h = (1.f - z) * n + z * h;
        if (ys != nullptr) {
            int tg = d ? (T_SEQ - 1 - c * CHK - i_) : (c * CHK + i_);
            ys[((size_t)tg * BATCH + b) * (2 * HID) + d * HID + j] = f2bf_rne(h);
        }
    };

    for (int i = 0; i < CHK; i += 2) {
        step(grA, gzA, gnA, i);
        if (i + 2 < CHK) { p = gaddr(i + 2); grA = p[j]; gzA = p[HID+j]; gnA = p[2*HID+j]; }
        step(grB, gzB, gnB, i + 1);
        if (i + 3 < CHK) { p = gaddr(i + 3); grB = p[j]; gzB = p[HID+j]; gnB = p[2*HID+j]; }
    }

    hbuf[((size_t)d * BATCH + b) * HID + j] = h;

    if (fin != nullptr && d == fin_dir) {
        fin[(size_t)b * 128 + j] = h;
    }
}

// ---------------------------------------------------------------------------
// Workspace layout (152.1 MiB total — chunked gi + bf16 ys to stay well
// under conservative ws_size):
//   ysA  bf16 (T,B,128)        67,108,864 B
//   ysB  bf16 (T,B,128)        67,108,864 B
//   gi   fp32 (2,CHK*B,192)    25,165,824 B
//   hbuf fp32 (2,B,64)            131,072 B
// Output = concat(hT[L1,bwd], hT[L2,fwd]); layer 3 and L2-bwd are dead code.
// ---------------------------------------------------------------------------
extern "C" void kernel_launch(void* const* d_in, const int* in_sizes, int n_in,
                              void* d_out, int out_size, void* d_ws, size_t ws_size,
                              hipStream_t stream) {
    (void)in_sizes; (void)n_in; (void)out_size; (void)ws_size;

    const float* mfcc = (const float*)d_in[0];
    const float* Wih0 = (const float*)d_in[1];   // (2, 192, 64)
    const float* Wih  = (const float*)d_in[2];   // (3, 2, 192, 128)
    const float* Whh  = (const float*)d_in[3];   // (4, 2, 192, 64)
    const float* bih  = (const float*)d_in[4];   // (4, 2, 192)
    const float* bhh  = (const float*)d_in[5];   // (4, 2, 192)
    float* out = (float*)d_out;                  // (256, 128)

    char* p = (char*)d_ws;
    ushort_t* ysA = (ushort_t*)p;  p += (size_t)T_SEQ * BATCH * 128 * 2;
    ushort_t* ysB = (ushort_t*)p;  p += (size_t)T_SEQ * BATCH * 128 * 2;
    float*    gi  = (float*)p;     p += (size_t)2 * CHK * BATCH * G3 * 4;
    float*    hb  = (float*)p;

    const dim3 ggrid2(CHK * BATCH / 64, 3, 2);
    const dim3 ggrid1(CHK * BATCH / 64, 3, 1);

    // ---- Layer 0 (K=64, fp32 input)
    for (int c = 0; c < NCHK; ++c) {
        gi_gemm_chunk<float, 64><<<ggrid2, 256, 0, stream>>>(
            mfcc, Wih0, (long)G3 * HID, bih, G3, gi, c);
        gru_recur_chunk<<<dim3(BATCH, 2), 64, 0, stream>>>(
            gi, Whh, bhh, ysA, hb, nullptr, -1, c);
    }

    // ---- Layer 1 (K=128, bf16 input). hT(bwd) -> out[:, 0:64]
    for (int c = 0; c < NCHK; ++c) {
        gi_gemm_chunk<ushort_t, 128><<<ggrid2, 256, 0, stream>>>(
            ysA, Wih, (long)G3 * 2 * HID, bih + 2 * G3, G3, gi, c);
        gru_recur_chunk<<<dim3(BATCH, 2), 64, 0, stream>>>(
            gi, Whh + 2 * (size_t)G3 * HID, bhh + 2 * G3, ysB, hb,
            (c == NCHK - 1) ? out : nullptr, 1, c);
    }

    // ---- Layer 2 forward only (K=128, bf16 input). hT -> out[:, 64:128]
    for (int c = 0; c < NCHK; ++c) {
        gi_gemm_chunk<ushort_t, 128><<<ggrid1, 256, 0, stream>>>(
            ysB, Wih + 2 * (size_t)G3 * 2 * HID, 0, bih + 4 * G3, 0, gi, c);
        gru_recur_chunk<<<dim3(BATCH, 1), 64, 0, stream>>>(
            gi, Whh + 4 * (size_t)G3 * HID, bhh + 4 * G3, nullptr, hb,
            (c == NCHK - 1) ? (out + HID) : nullptr, 0, c);
    }
}

// Round 10
// 3139.233 us; speedup vs baseline: 1.1969x; 1.1969x over previous
//
#include <hip/hip_runtime.h>
#include <cstddef>
#include <cstdint>

#define T_SEQ 1024
#define BATCH 256
#define HID   64
#define G3    192   // 3*H
#define CHK   128   // timesteps per chunk
#define NCHK  (T_SEQ / CHK)
#define KSLC  16    // k-slice per wave (4 waves * 16 = 64)

typedef unsigned short ushort_t;

__device__ __forceinline__ float sigm_f(float x) {
    return __fdividef(1.f, 1.f + __expf(-x));
}
__device__ __forceinline__ float tanh_f(float x) {
    return 1.f - __fdividef(2.f, 1.f + __expf(2.f * x));
}
__device__ __forceinline__ ushort_t f2bf_rne(float f) {
    uint32_t u = __float_as_uint(f);
    uint32_t r = (u + 0x7FFFu + ((u >> 16) & 1u)) >> 16;
    return (ushort_t)r;
}
__device__ __forceinline__ float bf2f(ushort_t u) {
    return __uint_as_float(((uint32_t)u) << 16);
}

__device__ __forceinline__ float4 load4f(const float* p) { return *(const float4*)p; }
__device__ __forceinline__ float4 load4f(const ushort_t* p) {
    ushort4 u = *(const ushort4*)p;
    float4 f;
    f.x = bf2f(u.x); f.y = bf2f(u.y); f.z = bf2f(u.z); f.w = bf2f(u.w);
    return f;
}

// ---------------------------------------------------------------------------
// Chunked input GEMM (unchanged from round 8's passing version).
// ---------------------------------------------------------------------------
template<typename TX, int K>
__global__ __launch_bounds__(256) void gi_gemm_chunk(
    const TX* __restrict__ x,
    const float* __restrict__ w,
    long w_dir_stride,
    const float* __restrict__ bias,
    long bias_dir_stride,
    float* __restrict__ gi,
    int c)
{
    __shared__ float xs[64][65];
    __shared__ float wsm[64][65];

    const int tid = threadIdx.x;
    const int mb  = blockIdx.x;
    const int nb  = blockIdx.y;
    const int d   = blockIdx.z;

    const int t_local = mb >> 2;
    const int boff    = (mb & 3) * 64;
    const int t_glob  = d ? (T_SEQ - 1 - c * CHK - t_local) : (c * CHK + t_local);

    const TX*    xg = x + ((size_t)t_glob * BATCH + boff) * K;
    const float* wg = w + (size_t)d * w_dir_stride + (size_t)nb * 64 * K;
    float* op = gi + ((size_t)d * CHK * BATCH + (size_t)t_local * BATCH + boff) * G3 + nb * 64;

    const int r0 = (tid >> 4) << 2;
    const int c0 = (tid & 15) << 2;
    float acc[4][4] = {};

    for (int kc = 0; kc < K; kc += 64) {
        #pragma unroll
        for (int i = 0; i < 4; ++i) {
            int ch  = tid + i * 256;
            int row = ch >> 4;
            int col = (ch & 15) << 2;
            float4 v = load4f(xg + (size_t)row * K + kc + col);
            xs[row][col+0] = v.x; xs[row][col+1] = v.y;
            xs[row][col+2] = v.z; xs[row][col+3] = v.w;
            float4 u = load4f(wg + (size_t)row * K + kc + col);
            wsm[row][col+0] = u.x; wsm[row][col+1] = u.y;
            wsm[row][col+2] = u.z; wsm[row][col+3] = u.w;
        }
        __syncthreads();
        #pragma unroll 8
        for (int k = 0; k < 64; ++k) {
            float a0 = xs[r0+0][k], a1 = xs[r0+1][k], a2 = xs[r0+2][k], a3 = xs[r0+3][k];
            float b0 = wsm[c0+0][k], b1 = wsm[c0+1][k], b2 = wsm[c0+2][k], b3 = wsm[c0+3][k];
            acc[0][0] = fmaf(a0,b0,acc[0][0]); acc[0][1] = fmaf(a0,b1,acc[0][1]);
            acc[0][2] = fmaf(a0,b2,acc[0][2]); acc[0][3] = fmaf(a0,b3,acc[0][3]);
            acc[1][0] = fmaf(a1,b0,acc[1][0]); acc[1][1] = fmaf(a1,b1,acc[1][1]);
            acc[1][2] = fmaf(a1,b2,acc[1][2]); acc[1][3] = fmaf(a1,b3,acc[1][3]);
            acc[2][0] = fmaf(a2,b0,acc[2][0]); acc[2][1] = fmaf(a2,b1,acc[2][1]);
            acc[2][2] = fmaf(a2,b2,acc[2][2]); acc[2][3] = fmaf(a2,b3,acc[2][3]);
            acc[3][0] = fmaf(a3,b0,acc[3][0]); acc[3][1] = fmaf(a3,b1,acc[3][1]);
            acc[3][2] = fmaf(a3,b2,acc[3][2]); acc[3][3] = fmaf(a3,b3,acc[3][3]);
        }
        __syncthreads();
    }

    const float* bp = bias + (size_t)d * bias_dir_stride + nb * 64;
    float4 bv = *(const float4*)(bp + c0);
    #pragma unroll
    for (int i = 0; i < 4; ++i) {
        float4 o;
        o.x = acc[i][0] + bv.x; o.y = acc[i][1] + bv.y;
        o.z = acc[i][2] + bv.z; o.w = acc[i][3] + bv.w;
        *(float4*)(op + (size_t)(r0 + i) * G3 + c0) = o;
    }
}

// ---------------------------------------------------------------------------
// Split-K GRU recurrence. 256 threads = 4 waves per (batch, dir).
// Lane j owns hidden unit j. Wave w owns k-slice [16w, 16w+16): 48 weight
// VGPRs/lane. Per step: each wave computes 16-deep partial dots (chain 64->16
// vs round-8), partials exchanged through LDS (parity double-buffer, ONE
// barrier/step), then ALL waves redundantly compute gates + h so each wave
// retains a lane-distributed h copy for its own readlane broadcasts.
// Round-8 evidence: 114us/dispatch, VALUBusy 28%, occupancy 5.6% -> serial
// dependency stalls. This cuts the critical path ~2140 -> ~300 cy/step.
// ---------------------------------------------------------------------------
__global__ __launch_bounds__(256) void gru_recur_chunk(
    const float* __restrict__ gi,
    const float* __restrict__ WhhL,   // (2, 192, 64)
    const float* __restrict__ bhhL,   // (2, 192)
    ushort_t* __restrict__ ys,
    float* __restrict__ hbuf,
    float* __restrict__ fin,
    int fin_dir,
    int c)
{
    __shared__ float pr[2][4][64];
    __shared__ float pz[2][4][64];
    __shared__ float pn[2][4][64];

    const int b = blockIdx.x;
    const int d = blockIdx.y;
    const int j = threadIdx.x & 63;
    // Force wave id into an SGPR so readlane's lane index is provably uniform
    // (avoids a compiler waterfall loop on v_readlane).
    const int w = __builtin_amdgcn_readfirstlane(threadIdx.x >> 6);

    // Wave w's 16-wide k-slice of Whh rows (r,z,n) for unit j.
    const float* W = WhhL + (size_t)d * G3 * HID;
    float wr[KSLC], wz[KSLC], wn[KSLC];
    #pragma unroll
    for (int q = 0; q < KSLC / 4; ++q) {
        float4 a = *(const float4*)(W + (size_t)j * HID + w * KSLC + 4*q);
        wr[4*q+0] = a.x; wr[4*q+1] = a.y; wr[4*q+2] = a.z; wr[4*q+3] = a.w;
        float4 bq = *(const float4*)(W + (size_t)(HID + j) * HID + w * KSLC + 4*q);
        wz[4*q+0] = bq.x; wz[4*q+1] = bq.y; wz[4*q+2] = bq.z; wz[4*q+3] = bq.w;
        float4 cq = *(const float4*)(W + (size_t)(2*HID + j) * HID + w * KSLC + 4*q);
        wn[4*q+0] = cq.x; wn[4*q+1] = cq.y; wn[4*q+2] = cq.z; wn[4*q+3] = cq.w;
    }
    const float* bh = bhhL + (size_t)d * G3;
    const float bhr = bh[j], bhz = bh[HID + j], bhn = bh[2*HID + j];

    const float* gib = gi + (size_t)d * CHK * BATCH * G3;

    // All waves hold a redundant lane-distributed copy of h.
    float h = (c == 0) ? 0.f : hbuf[((size_t)d * BATCH + b) * HID + j];

    auto gaddr = [&](int i) -> const float* {
        return gib + ((size_t)i * BATCH + b) * G3;
    };

    const float* p = gaddr(0);
    float grA = p[j], gzA = p[HID + j], gnA = p[2*HID + j];
    p = gaddr(1);
    float grB = p[j], gzB = p[HID + j], gnB = p[2*HID + j];

    const bool store_wave = (w == 0);

    auto step = [&](float gr, float gz, float gn, int i_, int par) {
        // Partial dot over this wave's k-slice.
        float ar = 0.f, az = 0.f, an = 0.f;
        #pragma unroll
        for (int kk = 0; kk < KSLC; ++kk) {
            float hk = __int_as_float(
                __builtin_amdgcn_readlane(__float_as_int(h), w * KSLC + kk));
            ar = fmaf(hk, wr[kk], ar);
            az = fmaf(hk, wz[kk], az);
            an = fmaf(hk, wn[kk], an);
        }
        pr[par][w][j] = ar;
        pz[par][w][j] = az;
        pn[par][w][j] = an;
        __syncthreads();
        // All waves redundantly reduce + gates, keeping h replicated per wave.
        float accr = bhr + ((pr[par][0][j] + pr[par][1][j]) + (pr[par][2][j] + pr[par][3][j]));
        float accz = bhz + ((pz[par][0][j] + pz[par][1][j]) + (pz[par][2][j] + pz[par][3][j]));
        float accn = bhn + ((pn[par][0][j] + pn[par][1][j]) + (pn[par][2][j] + pn[par][3][j]));
        float r = sigm_f(gr + accr);
        float z = sigm_f(gz + accz);
        float n = tanh_f(gn + r * accn);
        h = (1.f - z) * n + z * h;
        if (store_wave && ys != nullptr) {
            int tg = d ? (T_SEQ - 1 - c * CHK - i_) : (c * CHK + i_);
            ys[((size_t)tg * BATCH + b) * (2 * HID) + d * HID + j] = f2bf_rne(h);
        }
    };

    for (int i = 0; i < CHK; i += 2) {
        step(grA, gzA, gnA, i, 0);
        if (i + 2 < CHK) { p = gaddr(i + 2); grA = p[j]; gzA = p[HID+j]; gnA = p[2*HID+j]; }
        step(grB, gzB, gnB, i + 1, 1);
        if (i + 3 < CHK) { p = gaddr(i + 3); grB = p[j]; gzB = p[HID+j]; gnB = p[2*HID+j]; }
    }

    if (store_wave) {
        hbuf[((size_t)d * BATCH + b) * HID + j] = h;
        if (fin != nullptr && d == fin_dir) {
            fin[(size_t)b * 128 + j] = h;
        }
    }
}

// ---------------------------------------------------------------------------
// Workspace layout (152.1 MiB total):
//   ysA  bf16 (T,B,128)        67,108,864 B
//   ysB  bf16 (T,B,128)        67,108,864 B
//   gi   fp32 (2,CHK*B,192)    25,165,824 B
//   hbuf fp32 (2,B,64)            131,072 B
// Output = concat(hT[L1,bwd], hT[L2,fwd]); layer 3 and L2-bwd are dead code.
// ---------------------------------------------------------------------------
extern "C" void kernel_launch(void* const* d_in, const int* in_sizes, int n_in,
                              void* d_out, int out_size, void* d_ws, size_t ws_size,
                              hipStream_t stream) {
    (void)in_sizes; (void)n_in; (void)out_size; (void)ws_size;

    const float* mfcc = (const float*)d_in[0];
    const float* Wih0 = (const float*)d_in[1];   // (2, 192, 64)
    const float* Wih  = (const float*)d_in[2];   // (3, 2, 192, 128)
    const float* Whh  = (const float*)d_in[3];   // (4, 2, 192, 64)
    const float* bih  = (const float*)d_in[4];   // (4, 2, 192)
    const float* bhh  = (const float*)d_in[5];   // (4, 2, 192)
    float* out = (float*)d_out;                  // (256, 128)

    char* p = (char*)d_ws;
    ushort_t* ysA = (ushort_t*)p;  p += (size_t)T_SEQ * BATCH * 128 * 2;
    ushort_t* ysB = (ushort_t*)p;  p += (size_t)T_SEQ * BATCH * 128 * 2;
    float*    gi  = (float*)p;     p += (size_t)2 * CHK * BATCH * G3 * 4;
    float*    hb  = (float*)p;

    const dim3 ggrid2(CHK * BATCH / 64, 3, 2);
    const dim3 ggrid1(CHK * BATCH / 64, 3, 1);

    // ---- Layer 0 (K=64, fp32 input)
    for (int c = 0; c < NCHK; ++c) {
        gi_gemm_chunk<float, 64><<<ggrid2, 256, 0, stream>>>(
            mfcc, Wih0, (long)G3 * HID, bih, G3, gi, c);
        gru_recur_chunk<<<dim3(BATCH, 2), 256, 0, stream>>>(
            gi, Whh, bhh, ysA, hb, nullptr, -1, c);
    }

    // ---- Layer 1 (K=128, bf16 input). hT(bwd) -> out[:, 0:64]
    for (int c = 0; c < NCHK; ++c) {
        gi_gemm_chunk<ushort_t, 128><<<ggrid2, 256, 0, stream>>>(
            ysA, Wih, (long)G3 * 2 * HID, bih + 2 * G3, G3, gi, c);
        gru_recur_chunk<<<dim3(BATCH, 2), 256, 0, stream>>>(
            gi, Whh + 2 * (size_t)G3 * HID, bhh + 2 * G3, ysB, hb,
            (c == NCHK - 1) ? out : nullptr, 1, c);
    }

    // ---- Layer 2 forward only (K=128, bf16 input). hT -> out[:, 64:128]
    for (int c = 0; c < NCHK; ++c) {
        gi_gemm_chunk<ushort_t, 128><<<ggrid1, 256, 0, stream>>>(
            ysB, Wih + 2 * (size_t)G3 * 2 * HID, 0, bih + 4 * G3, 0, gi, c);
        gru_recur_chunk<<<dim3(BATCH, 1), 256, 0, stream>>>(
            gi, Whh + 4 * (size_t)G3 * HID, bhh + 4 * G3, nullptr, hb,
            (c == NCHK - 1) ? (out + HID) : nullptr, 0, c);
    }
}

// Round 13
// 3135.196 us; speedup vs baseline: 1.1985x; 1.0013x over previous
//
#include <hip/hip_runtime.h>
#include <cstddef>
#include <cstdint>

#define T_SEQ 1024
#define BATCH 256
#define HID   64
#define G3    192   // 3*H
#define CHK   128   // timesteps per chunk
#define NCHK  (T_SEQ / CHK)
#define KSLC  16    // k-slice per wave (4 waves * 16 = 64)

typedef unsigned short ushort_t;

__device__ __forceinline__ float sigm_f(float x) {
    return __fdividef(1.f, 1.f + __expf(-x));
}
__device__ __forceinline__ float tanh_f(float x) {
    return 1.f - __fdividef(2.f, 1.f + __expf(2.f * x));
}
__device__ __forceinline__ ushort_t f2bf_rne(float f) {
    uint32_t u = __float_as_uint(f);
    uint32_t r = (u + 0x7FFFu + ((u >> 16) & 1u)) >> 16;
    return (ushort_t)r;
}
__device__ __forceinline__ float bf2f(ushort_t u) {
    return __uint_as_float(((uint32_t)u) << 16);
}

__device__ __forceinline__ float4 load4f(const float* p) { return *(const float4*)p; }
__device__ __forceinline__ float4 load4f(const ushort_t* p) {
    ushort4 u = *(const ushort4*)p;
    float4 f;
    f.x = bf2f(u.x); f.y = bf2f(u.y); f.z = bf2f(u.z); f.w = bf2f(u.w);
    return f;
}

// ---------------------------------------------------------------------------
// Chunked input GEMM (unchanged — measured ~45 TF fp32, second-order target).
// ---------------------------------------------------------------------------
template<typename TX, int K>
__global__ __launch_bounds__(256) void gi_gemm_chunk(
    const TX* __restrict__ x,
    const float* __restrict__ w,
    long w_dir_stride,
    const float* __restrict__ bias,
    long bias_dir_stride,
    float* __restrict__ gi,
    int c)
{
    __shared__ float xs[64][65];
    __shared__ float wsm[64][65];

    const int tid = threadIdx.x;
    const int mb  = blockIdx.x;
    const int nb  = blockIdx.y;
    const int d   = blockIdx.z;

    const int t_local = mb >> 2;
    const int boff    = (mb & 3) * 64;
    const int t_glob  = d ? (T_SEQ - 1 - c * CHK - t_local) : (c * CHK + t_local);

    const TX*    xg = x + ((size_t)t_glob * BATCH + boff) * K;
    const float* wg = w + (size_t)d * w_dir_stride + (size_t)nb * 64 * K;
    float* op = gi + ((size_t)d * CHK * BATCH + (size_t)t_local * BATCH + boff) * G3 + nb * 64;

    const int r0 = (tid >> 4) << 2;
    const int c0 = (tid & 15) << 2;
    float acc[4][4] = {};

    for (int kc = 0; kc < K; kc += 64) {
        #pragma unroll
        for (int i = 0; i < 4; ++i) {
            int ch  = tid + i * 256;
            int row = ch >> 4;
            int col = (ch & 15) << 2;
            float4 v = load4f(xg + (size_t)row * K + kc + col);
            xs[row][col+0] = v.x; xs[row][col+1] = v.y;
            xs[row][col+2] = v.z; xs[row][col+3] = v.w;
            float4 u = load4f(wg + (size_t)row * K + kc + col);
            wsm[row][col+0] = u.x; wsm[row][col+1] = u.y;
            wsm[row][col+2] = u.z; wsm[row][col+3] = u.w;
        }
        __syncthreads();
        #pragma unroll 8
        for (int k = 0; k < 64; ++k) {
            float a0 = xs[r0+0][k], a1 = xs[r0+1][k], a2 = xs[r0+2][k], a3 = xs[r0+3][k];
            float b0 = wsm[c0+0][k], b1 = wsm[c0+1][k], b2 = wsm[c0+2][k], b3 = wsm[c0+3][k];
            acc[0][0] = fmaf(a0,b0,acc[0][0]); acc[0][1] = fmaf(a0,b1,acc[0][1]);
            acc[0][2] = fmaf(a0,b2,acc[0][2]); acc[0][3] = fmaf(a0,b3,acc[0][3]);
            acc[1][0] = fmaf(a1,b0,acc[1][0]); acc[1][1] = fmaf(a1,b1,acc[1][1]);
            acc[1][2] = fmaf(a1,b2,acc[1][2]); acc[1][3] = fmaf(a1,b3,acc[1][3]);
            acc[2][0] = fmaf(a2,b0,acc[2][0]); acc[2][1] = fmaf(a2,b1,acc[2][1]);
            acc[2][2] = fmaf(a2,b2,acc[2][2]); acc[2][3] = fmaf(a2,b3,acc[2][3]);
            acc[3][0] = fmaf(a3,b0,acc[3][0]); acc[3][1] = fmaf(a3,b1,acc[3][1]);
            acc[3][2] = fmaf(a3,b2,acc[3][2]); acc[3][3] = fmaf(a3,b3,acc[3][3]);
        }
        __syncthreads();
    }

    const float* bp = bias + (size_t)d * bias_dir_stride + nb * 64;
    float4 bv = *(const float4*)(bp + c0);
    #pragma unroll
    for (int i = 0; i < 4; ++i) {
        float4 o;
        o.x = acc[i][0] + bv.x; o.y = acc[i][1] + bv.y;
        o.z = acc[i][2] + bv.z; o.w = acc[i][3] + bv.w;
        *(float4*)(op + (size_t)(r0 + i) * G3 + c0) = o;
    }
}

// ---------------------------------------------------------------------------
// Split-K GRU recurrence, round-11 fix: round-10 showed VGPR_Count=40 -> the
// wr/wz/wn arrays were scratch-demoted (rule-#20 failure: the compiler kept a
// runtime kk loop inside the twice-called lambda). Now: 12 NAMED float4
// weight registers + hand-unrolled 16-deep dot with literal readlane offsets
// (kb is an SGPR). __launch_bounds__(256,1) removes any occupancy-driven
// VGPR cap. Everything else identical to the passing round-10 kernel.
// ---------------------------------------------------------------------------
__global__ __launch_bounds__(256, 1) void gru_recur_chunk(
    const float* __restrict__ gi,
    const float* __restrict__ WhhL,   // (2, 192, 64)
    const float* __restrict__ bhhL,   // (2, 192)
    ushort_t* __restrict__ ys,
    float* __restrict__ hbuf,
    float* __restrict__ fin,
    int fin_dir,
    int c)
{
    __shared__ float pr[2][4][64];
    __shared__ float pz[2][4][64];
    __shared__ float pn[2][4][64];

    const int b = blockIdx.x;
    const int d = blockIdx.y;
    const int j = threadIdx.x & 63;
    // Wave id in an SGPR (uniform) -> readlane indices kb+K are SGPR+literal.
    const int w  = __builtin_amdgcn_readfirstlane(threadIdx.x >> 6);
    const int kb = w * KSLC;

    // Wave w's 16-wide k-slice of Whh rows (r,z,n) for unit j, in 12 named
    // float4 registers (48 VGPRs) — cannot be scratch-demoted.
    const float* W = WhhL + (size_t)d * G3 * HID;
    const float* wrp = W + (size_t)j * HID + kb;
    const float* wzp = W + (size_t)(HID + j) * HID + kb;
    const float* wnp = W + (size_t)(2 * HID + j) * HID + kb;
    const float4 wr0 = load4f(wrp + 0), wr1 = load4f(wrp + 4), wr2 = load4f(wrp + 8), wr3 = load4f(wrp + 12);
    const float4 wz0 = load4f(wzp + 0), wz1 = load4f(wzp + 4), wz2 = load4f(wzp + 8), wz3 = load4f(wzp + 12);
    const float4 wn0 = load4f(wnp + 0), wn1 = load4f(wnp + 4), wn2 = load4f(wnp + 8), wn3 = load4f(wnp + 12);

    const float* bh = bhhL + (size_t)d * G3;
    const float bhr = bh[j], bhz = bh[HID + j], bhn = bh[2*HID + j];

    const float* gib = gi + (size_t)d * CHK * BATCH * G3;

    // All waves hold a redundant lane-distributed copy of h.
    float h = (c == 0) ? 0.f : hbuf[((size_t)d * BATCH + b) * HID + j];

    auto gaddr = [&](int i) -> const float* {
        return gib + ((size_t)i * BATCH + b) * G3;
    };

    const float* p = gaddr(0);
    float grA = p[j], gzA = p[HID + j], gnA = p[2*HID + j];
    p = gaddr(1);
    float grB = p[j], gzB = p[HID + j], gnB = p[2*HID + j];

    const bool store_wave = (w == 0);

#define RL(K) __int_as_float(__builtin_amdgcn_readlane(__float_as_int(h), kb + (K)))

    auto step = [&](float gr, float gz, float gn, int i_, int par) {
        // 16-deep partial dot, fully static (literal readlane K, named regs).
        float ar = 0.f, az = 0.f, an = 0.f;
        float hk;
        hk = RL(0);  ar = fmaf(hk, wr0.x, ar); az = fmaf(hk, wz0.x, az); an = fmaf(hk, wn0.x, an);
        hk = RL(1);  ar = fmaf(hk, wr0.y, ar); az = fmaf(hk, wz0.y, az); an = fmaf(hk, wn0.y, an);
        hk = RL(2);  ar = fmaf(hk, wr0.z, ar); az = fmaf(hk, wz0.z, az); an = fmaf(hk, wn0.z, an);
        hk = RL(3);  ar = fmaf(hk, wr0.w, ar); az = fmaf(hk, wz0.w, az); an = fmaf(hk, wn0.w, an);
        hk = RL(4);  ar = fmaf(hk, wr1.x, ar); az = fmaf(hk, wz1.x, az); an = fmaf(hk, wn1.x, an);
        hk = RL(5);  ar = fmaf(hk, wr1.y, ar); az = fmaf(hk, wz1.y, az); an = fmaf(hk, wn1.y, an);
        hk = RL(6);  ar = fmaf(hk, wr1.z, ar); az = fmaf(hk, wz1.z, az); an = fmaf(hk, wn1.z, an);
        hk = RL(7);  ar = fmaf(hk, wr1.w, ar); az = fmaf(hk, wz1.w, az); an = fmaf(hk, wn1.w, an);
        hk = RL(8);  ar = fmaf(hk, wr2.x, ar); az = fmaf(hk, wz2.x, az); an = fmaf(hk, wn2.x, an);
        hk = RL(9);  ar = fmaf(hk, wr2.y, ar); az = fmaf(hk, wz2.y, az); an = fmaf(hk, wn2.y, an);
        hk = RL(10); ar = fmaf(hk, wr2.z, ar); az = fmaf(hk, wz2.z, az); an = fmaf(hk, wn2.z, an);
        hk = RL(11); ar = fmaf(hk, wr2.w, ar); az = fmaf(hk, wz2.w, az); an = fmaf(hk, wn2.w, an);
        hk = RL(12); ar = fmaf(hk, wr3.x, ar); az = fmaf(hk, wz3.x, az); an = fmaf(hk, wn3.x, an);
        hk = RL(13); ar = fmaf(hk, wr3.y, ar); az = fmaf(hk, wz3.y, az); an = fmaf(hk, wn3.y, an);
        hk = RL(14); ar = fmaf(hk, wr3.z, ar); az = fmaf(hk, wz3.z, az); an = fmaf(hk, wn3.z, an);
        hk = RL(15); ar = fmaf(hk, wr3.w, ar); az = fmaf(hk, wz3.w, az); an = fmaf(hk, wn3.w, an);

        pr[par][w][j] = ar;
        pz[par][w][j] = az;
        pn[par][w][j] = an;
        __syncthreads();
        // All waves redundantly reduce + gates, keeping h replicated per wave.
        float accr = bhr + ((pr[par][0][j] + pr[par][1][j]) + (pr[par][2][j] + pr[par][3][j]));
        float accz = bhz + ((pz[par][0][j] + pz[par][1][j]) + (pz[par][2][j] + pz[par][3][j]));
        float accn = bhn + ((pn[par][0][j] + pn[par][1][j]) + (pn[par][2][j] + pn[par][3][j]));
        float r = sigm_f(gr + accr);
        float z = sigm_f(gz + accz);
        float n = tanh_f(gn + r * accn);
        h = (1.f - z) * n + z * h;
        if (store_wave && ys != nullptr) {
            int tg = d ? (T_SEQ - 1 - c * CHK - i_) : (c * CHK + i_);
            ys[((size_t)tg * BATCH + b) * (2 * HID) + d * HID + j] = f2bf_rne(h);
        }
    };
#undef RL

    for (int i = 0; i < CHK; i += 2) {
        step(grA, gzA, gnA, i, 0);
        if (i + 2 < CHK) { p = gaddr(i + 2); grA = p[j]; gzA = p[HID+j]; gnA = p[2*HID+j]; }
        step(grB, gzB, gnB, i + 1, 1);
        if (i + 3 < CHK) { p = gaddr(i + 3); grB = p[j]; gzB = p[HID+j]; gnB = p[2*HID+j]; }
    }

    if (store_wave) {
        hbuf[((size_t)d * BATCH + b) * HID + j] = h;
        if (fin != nullptr && d == fin_dir) {
            fin[(size_t)b * 128 + j] = h;
        }
    }
}

// ---------------------------------------------------------------------------
// Workspace layout (152.1 MiB total):
//   ysA  bf16 (T,B,128)        67,108,864 B
//   ysB  bf16 (T,B,128)        67,108,864 B
//   gi   fp32 (2,CHK*B,192)    25,165,824 B
//   hbuf fp32 (2,B,64)            131,072 B
// Output = concat(hT[L1,bwd], hT[L2,fwd]); layer 3 and L2-bwd are dead code.
// ---------------------------------------------------------------------------
extern "C" void kernel_launch(void* const* d_in, const int* in_sizes, int n_in,
                              void* d_out, int out_size, void* d_ws, size_t ws_size,
                              hipStream_t stream) {
    (void)in_sizes; (void)n_in; (void)out_size; (void)ws_size;

    const float* mfcc = (const float*)d_in[0];
    const float* Wih0 = (const float*)d_in[1];   // (2, 192, 64)
    const float* Wih  = (const float*)d_in[2];   // (3, 2, 192, 128)
    const float* Whh  = (const float*)d_in[3];   // (4, 2, 192, 64)
    const float* bih  = (const float*)d_in[4];   // (4, 2, 192)
    const float* bhh  = (const float*)d_in[5];   // (4, 2, 192)
    float* out = (float*)d_out;                  // (256, 128)

    char* p = (char*)d_ws;
    ushort_t* ysA = (ushort_t*)p;  p += (size_t)T_SEQ * BATCH * 128 * 2;
    ushort_t* ysB = (ushort_t*)p;  p += (size_t)T_SEQ * BATCH * 128 * 2;
    float*    gi  = (float*)p;     p += (size_t)2 * CHK * BATCH * G3 * 4;
    float*    hb  = (float*)p;

    const dim3 ggrid2(CHK * BATCH / 64, 3, 2);
    const dim3 ggrid1(CHK * BATCH / 64, 3, 1);

    // ---- Layer 0 (K=64, fp32 input)
    for (int c = 0; c < NCHK; ++c) {
        gi_gemm_chunk<float, 64><<<ggrid2, 256, 0, stream>>>(
            mfcc, Wih0, (long)G3 * HID, bih, G3, gi, c);
        gru_recur_chunk<<<dim3(BATCH, 2), 256, 0, stream>>>(
            gi, Whh, bhh, ysA, hb, nullptr, -1, c);
    }

    // ---- Layer 1 (K=128, bf16 input). hT(bwd) -> out[:, 0:64]
    for (int c = 0; c < NCHK; ++c) {
        gi_gemm_chunk<ushort_t, 128><<<ggrid2, 256, 0, stream>>>(
            ysA, Wih, (long)G3 * 2 * HID, bih + 2 * G3, G3, gi, c);
        gru_recur_chunk<<<dim3(BATCH, 2), 256, 0, stream>>>(
            gi, Whh + 2 * (size_t)G3 * HID, bhh + 2 * G3, ysB, hb,
            (c == NCHK - 1) ? out : nullptr, 1, c);
    }

    // ---- Layer 2 forward only (K=128, bf16 input). hT -> out[:, 64:128]
    for (int c = 0; c < NCHK; ++c) {
        gi_gemm_chunk<ushort_t, 128><<<ggrid1, 256, 0, stream>>>(
            ysB, Wih + 2 * (size_t)G3 * 2 * HID, 0, bih + 4 * G3, 0, gi, c);
        gru_recur_chunk<<<dim3(BATCH, 1), 256, 0, stream>>>(
            gi, Whh + 4 * (size_t)G3 * HID, bhh + 4 * G3, nullptr, hb,
            (c == NCHK - 1) ? (out + HID) : nullptr, 0, c);
    }
}